// Round 9
// baseline (161.144 us; speedup 1.0000x reference)
//
#include <hip/hip_runtime.h>

// Dims fixed by setup_inputs: B=2, S=2048, D=1024, F=4096, T=8
#define N_ROWS 4096
#define DDIM   1024
#define FDIM   4096

typedef unsigned short u16;
typedef __attribute__((ext_vector_type(8))) _Float16 f16x8;
typedef __attribute__((ext_vector_type(4))) float f32x4;

#define MFMA16(a, b, c) __builtin_amdgcn_mfma_f32_16x16x32_f16((a), (b), (c), 0, 0, 0)

static __device__ __forceinline__ u16 f2h_bits(float f) {
    _Float16 h = (_Float16)f;
    return __builtin_bit_cast(u16, h);
}
static __device__ __forceinline__ void gload_lds16(const u16* g, u16* l) {
    __builtin_amdgcn_global_load_lds((const __attribute__((address_space(1))) unsigned*)g,
                                     (__attribute__((address_space(3))) unsigned*)l, 16, 0, 0);
}

// ---- fused prepass: x -> (xh, xl) fp16 ; wup -> wh fp16 ; wdown -> wd fp16 ;
//      zero colsum. One launch. ----
__global__ __launch_bounds__(256) void split_all(
    const float* __restrict__ x, const float* __restrict__ wup,
    const float* __restrict__ wdown,
    u16* __restrict__ xh, u16* __restrict__ xl,
    u16* __restrict__ wh, u16* __restrict__ wd, float* __restrict__ colsum)
{
    const int N4 = (N_ROWS * DDIM) / 4;   // 1,048,576 float4 per array
    int i = blockIdx.x * 256 + threadIdx.x;
    if (i < FDIM / 4) ((float4*)colsum)[i] = (float4){0.f, 0.f, 0.f, 0.f};
    const int stride = gridDim.x * 256;
    for (; i < 3 * N4; i += stride) {
        const int r = i >> 20;            // N4 == 2^20
        const int j = i & (N4 - 1);
        if (r == 0) {
            float4 v = ((const float4*)x)[j];
            ushort4 h, l;
            h.x = f2h_bits(v.x); h.y = f2h_bits(v.y);
            h.z = f2h_bits(v.z); h.w = f2h_bits(v.w);
            l.x = f2h_bits(v.x - (float)__builtin_bit_cast(_Float16, h.x));
            l.y = f2h_bits(v.y - (float)__builtin_bit_cast(_Float16, h.y));
            l.z = f2h_bits(v.z - (float)__builtin_bit_cast(_Float16, h.z));
            l.w = f2h_bits(v.w - (float)__builtin_bit_cast(_Float16, h.w));
            ((ushort4*)xh)[j] = h;
            ((ushort4*)xl)[j] = l;
        } else {
            const float4 v = (r == 1) ? ((const float4*)wup)[j] : ((const float4*)wdown)[j];
            ushort4 h;
            h.x = f2h_bits(v.x); h.y = f2h_bits(v.y);
            h.z = f2h_bits(v.z); h.w = f2h_bits(v.w);
            if (r == 1) ((ushort4*)wh)[j] = h; else ((ushort4*)wd)[j] = h;
        }
    }
}

// ---- up-GEMM: 128x128 tile, 256 threads / 4 waves (wave-tile 64x64),
//      fp16 16x16x32, 2-product split; xh+B staged via LDS (3-slot BK=32,
//      counted vmcnt), xl REGISTER-staged 1 tile ahead (wave-private rows).
//      48KB LDS + ~64 AGPR acc -> 3 blocks/CU of independent waves.
//      Fused LIF + column-sum epilogue. ----
__global__ __launch_bounds__(256, 3) void up_mfma(
    const u16* __restrict__ xh, const u16* __restrict__ xl,
    const u16* __restrict__ wh,
    const float* __restrict__ beta, const int* __restrict__ Tp,
    u16* __restrict__ rate, float* __restrict__ colsum)
{
    // slot = Ah[128][32] (4096 u16) + B[128][32] (4096 u16) = 16KB; 3 slots = 48KB
    __shared__ __align__(16) u16 lds[3 * 8192];

    const int t = threadIdx.x;
    const int l = t & 63, w = t >> 6;          // 4 waves
    const int wm = w >> 1, wn = w & 1;         // 2M x 2N, wave-tile 64x64

    // per-XCD 8bm x 16bn rectangle (grid 32x32 = 1024 blocks)
    const int flat = blockIdx.y * gridDim.x + blockIdx.x;   // 0..1023
    const int xcd = flat & 7, wi = flat >> 3;               // wi 0..127
    const int bm = ((xcd & 3) * 8 + (wi & 7)) * 128;
    const int bn = ((xcd >> 2) * 16 + (wi >> 3)) * 128;

    // LDS staging: dest linear t*16B; source k pre-swizzled (involution w/ read XOR)
    // issue j covers rows j*64 + (t>>2); 4-slot key = (row>>1)&3 = (t>>3)&3
    const int koff = (((t & 3) ^ ((t >> 3) & 3)) << 3);
    const size_t gA0 = (size_t)(bm + (t >> 2)) * DDIM + koff;
    const size_t gA1 = gA0 + (size_t)64 * DDIM;
    const size_t gB0 = (size_t)(bn + (t >> 2)) * DDIM + koff;
    const size_t gB1 = gB0 + (size_t)64 * DDIM;
    const int dst = t * 8;

#define STG(slot, step) do {                                                  \
    const size_t k0_ = (size_t)(step) << 5;                                   \
    u16* Lb_ = &lds[(slot) * 8192];                                           \
    gload_lds16(xh + gA0 + k0_, Lb_ + dst);                                   \
    gload_lds16(xh + gA1 + k0_, Lb_ + 2048 + dst);                            \
    gload_lds16(wh + gB0 + k0_, Lb_ + 4096 + dst);                            \
    gload_lds16(wh + gB1 + k0_, Lb_ + 6144 + dst);                            \
} while (0)

    // fragment reads (0-conflict XOR, proven R4/R6/R8)
    const int lr = l & 15, lk = l >> 4;
    const int psl = ((lk ^ ((lr >> 1) & 3)) << 3);

    // xl register staging: wave-private rows, frag m at row wm*64+m*16+lr
    const u16* xlbase = xl + (size_t)(bm + wm * 64 + lr) * DDIM + lk * 8;

    f32x4 acc[4][4];
#pragma unroll
    for (int m = 0; m < 4; ++m)
#pragma unroll
        for (int n = 0; n < 4; ++n) acc[m][n] = (f32x4){0.f, 0.f, 0.f, 0.f};

    f16x8 cur[4], nxt[4];
    // prologue: regs(0) then stage(0), then stage(1)
#pragma unroll
    for (int m = 0; m < 4; ++m)
        nxt[m] = *(const f16x8*)(xlbase + (size_t)(m * 16) * DDIM);
    STG(0, 0);
    STG(1, 1);

    const int NT = DDIM / 32;   // 32
#pragma unroll 1
    for (int ts = 0; ts < NT; ++ts) {
        // counted wait: stage(ts) (and regs via compiler auto-waits) landed.
        if (ts == 0) { asm volatile("s_waitcnt vmcnt(4)" ::: "memory"); }
        else         { asm volatile("s_waitcnt vmcnt(8)" ::: "memory"); }
        __builtin_amdgcn_s_barrier();

        // consume regs(ts); issue regs(ts+1) then stage(ts+2)
#pragma unroll
        for (int m = 0; m < 4; ++m) cur[m] = nxt[m];
        if (ts + 1 < NT) {
            const size_t ko = (size_t)((ts + 1) << 5);
#pragma unroll
            for (int m = 0; m < 4; ++m)
                nxt[m] = *(const f16x8*)(xlbase + (size_t)(m * 16) * DDIM + ko);
        }
        if (ts + 2 < NT) STG((ts + 2) % 3, ts + 2);

        const int sb = (ts % 3) * 8192;
        f16x8 ah[4], b[4];
#pragma unroll
        for (int m = 0; m < 4; ++m)
            ah[m] = *(const f16x8*)&lds[sb + (wm * 64 + m * 16 + lr) * 32 + psl];
#pragma unroll
        for (int n = 0; n < 4; ++n)
            b[n] = *(const f16x8*)&lds[sb + 4096 + (wn * 64 + n * 16 + lr) * 32 + psl];

        __builtin_amdgcn_s_setprio(1);
#pragma unroll
        for (int m = 0; m < 4; ++m)
#pragma unroll
            for (int n = 0; n < 4; ++n) {
                f32x4 c = acc[m][n];
                c = MFMA16(ah[m], b[n], c);     // xh * wh
                c = MFMA16(cur[m], b[n], c);    // xl * wh
                acc[m][n] = c;
            }
        __builtin_amdgcn_s_setprio(0);
    }
#undef STG

    // ---- epilogue: LIF recurrence, rate write, fused column sums ----
    const int T = Tp[0];
    const float invT = 1.0f / (float)T;
    const int fbase = bn + wn * 64;
    float betav[4], colacc[4];
#pragma unroll
    for (int n = 0; n < 4; ++n) { betav[n] = beta[fbase + n * 16 + lr]; colacc[n] = 0.f; }

#pragma unroll
    for (int m = 0; m < 4; ++m) {
#pragma unroll
        for (int r = 0; r < 4; ++r) {
            const int row = bm + wm * 64 + m * 16 + lk * 4 + r;
            u16* rp = rate + (size_t)row * FDIM + fbase + lr;
#pragma unroll
            for (int n = 0; n < 4; ++n) {
                const float h = acc[m][n][r];
                const float bet = betav[n];
                float v = 0.f, ss = 0.f;
                if (T == 8) {
#pragma unroll
                    for (int tt = 0; tt < 8; ++tt) {
                        v = fmaf(bet, v, h);
                        float s = (v > 1.0f) ? 1.0f : 0.0f;
                        ss += s; v -= s;
                    }
                } else {
                    for (int tt = 0; tt < T; ++tt) {
                        v = fmaf(bet, v, h);
                        float s = (v > 1.0f) ? 1.0f : 0.0f;
                        ss += s; v -= s;
                    }
                }
                const float rv = ss * invT;                 // exact k/8 (fp16-exact)
                rp[n * 16] = f2h_bits(rv);
                colacc[n] += rv;
            }
        }
    }
#pragma unroll
    for (int n = 0; n < 4; ++n) {
        float ca = colacc[n];
        ca += __shfl_xor(ca, 16, 64);
        ca += __shfl_xor(ca, 32, 64);
        if (lk == 0) atomicAdd(&colsum[fbase + n * 16 + lr], ca);  // exact eighths
    }
}

// ---- down-GEMM: 128x128 tile, BK=64, 8 waves (2Mx4N, wave-tile 64x32),
//      fp16 16x16x32 MFMA, 3-slot counted-vmcnt rotation, 0-conflict XOR LDS.
//      out = rate(fp16) @ wd(fp16)^T, fp32 out ----
__global__ __launch_bounds__(512, 1) void down_mfma(
    const u16* __restrict__ rate, const u16* __restrict__ wd,
    float* __restrict__ out)
{
    // slot = A[128][64] + B[128][64] u16 = 32KB; 3 slots = 96KB
    __shared__ __align__(16) u16 lds[3 * 16384];

    const int t = threadIdx.x;
    const int l = t & 63, w = t >> 6;
    const int wm = w >> 2, wn = w & 3;          // wave tile 64x32

    // per-XCD 8bm x 4bn rectangle
    const int flat = blockIdx.y * gridDim.x + blockIdx.x;   // 0..255
    const int xcd = flat & 7, wi = flat >> 3;               // wi 0..31
    const int bm = ((xcd & 3) * 8 + (wi & 7)) * 128;
    const int bn = ((xcd >> 2) * 4 + (wi >> 3)) * 128;

    // staging: 4 issues/thread/tile; key = row&7 involution
    const int srow = t >> 3;                                // 0..63
    const int koff = (((t & 7) ^ ((t >> 3) & 7)) << 3);
    const size_t gA0 = (size_t)(bm + srow) * FDIM + koff;
    const size_t gA1 = gA0 + (size_t)64 * FDIM;
    const size_t gB0 = (size_t)(bn + srow) * FDIM + koff;
    const size_t gB1 = gB0 + (size_t)64 * FDIM;
    const int dst = t * 8;

#define STD(slot, step) do {                                                  \
    const size_t k0_ = (size_t)(step) << 6;                                   \
    u16* Lb_ = &lds[(slot) * 16384];                                          \
    gload_lds16(rate + gA0 + k0_, Lb_ + dst);                                 \
    gload_lds16(rate + gA1 + k0_, Lb_ + 4096 + dst);                          \
    gload_lds16(wd + gB0 + k0_, Lb_ + 8192 + dst);                            \
    gload_lds16(wd + gB1 + k0_, Lb_ + 12288 + dst);                           \
} while (0)

    const int lr = l & 15, lk = l >> 4;
    const int key = lr & 7;
    const int ps0 = ((0 * 4 + lk) ^ key) << 3;
    const int ps1 = ((1 * 4 + lk) ^ key) << 3;

    f32x4 acc[4][2];
#pragma unroll
    for (int m = 0; m < 4; ++m) {
        acc[m][0] = (f32x4){0.f, 0.f, 0.f, 0.f};
        acc[m][1] = (f32x4){0.f, 0.f, 0.f, 0.f};
    }

    STD(0, 0);
    STD(1, 1);

    const int NT = FDIM / 64;   // 64
#pragma unroll 1
    for (int ts = 0; ts < NT; ++ts) {
        if (ts + 1 < NT) { asm volatile("s_waitcnt vmcnt(4)" ::: "memory"); }
        else             { asm volatile("s_waitcnt vmcnt(0)" ::: "memory"); }
        __builtin_amdgcn_s_barrier();

        if (ts + 2 < NT) STD((ts + 2) % 3, ts + 2);

        const int sb = (ts % 3) * 16384;
        f16x8 a[4][2], b[2][2];
#pragma unroll
        for (int m = 0; m < 4; ++m) {
            const int ro = sb + (wm * 64 + m * 16 + lr) * 64;
            a[m][0] = *(const f16x8*)&lds[ro + ps0];
            a[m][1] = *(const f16x8*)&lds[ro + ps1];
        }
#pragma unroll
        for (int n = 0; n < 2; ++n) {
            const int ro = sb + 8192 + (wn * 32 + n * 16 + lr) * 64;
            b[n][0] = *(const f16x8*)&lds[ro + ps0];
            b[n][1] = *(const f16x8*)&lds[ro + ps1];
        }
        __builtin_amdgcn_s_setprio(1);
#pragma unroll
        for (int m = 0; m < 4; ++m)
#pragma unroll
            for (int n = 0; n < 2; ++n) {
                f32x4 c = acc[m][n];
                c = MFMA16(a[m][0], b[n][0], c);
                c = MFMA16(a[m][1], b[n][1], c);
                acc[m][n] = c;
            }
        __builtin_amdgcn_s_setprio(0);
    }
#undef STD

#pragma unroll
    for (int n = 0; n < 2; ++n) {
        const int d = bn + wn * 32 + n * 16 + lr;
#pragma unroll
        for (int m = 0; m < 4; ++m) {
            const int row0 = bm + wm * 64 + m * 16 + lk * 4;
#pragma unroll
            for (int r = 0; r < 4; ++r)
                out[(size_t)(row0 + r) * DDIM + d] = acc[m][n][r];
        }
    }
}

// ---- rate_per_unit ----
__global__ void finalize_rpu(const float* __restrict__ colsum, float* __restrict__ out_rpu) {
    const int f = blockIdx.x * 256 + threadIdx.x;
    out_rpu[f] = colsum[f] * (1.0f / (float)N_ROWS);
}

extern "C" void kernel_launch(void* const* d_in, const int* in_sizes, int n_in,
                              void* d_out, int out_size, void* d_ws, size_t ws_size,
                              hipStream_t stream) {
    const float* x     = (const float*)d_in[0];
    const float* wup   = (const float*)d_in[1];
    const float* wdown = (const float*)d_in[2];
    const float* beta  = (const float*)d_in[3];
    const int*   Tp    = (const int*)d_in[4];

    float* out     = (float*)d_out;
    float* out_rpu = out + (size_t)N_ROWS * DDIM;

    char* ws = (char*)d_ws;
    u16* rate = (u16*)ws;                                   // 33,554,432 B
    u16* xh   = (u16*)(ws + 33554432);                      //  8,388,608 B
    u16* xl   = (u16*)(ws + 33554432 + 8388608);
    u16* wh   = (u16*)(ws + 33554432 + 2 * 8388608);
    u16* wd   = (u16*)(ws + 33554432 + 3 * 8388608);
    float* colsum = (float*)(ws + 33554432 + 4 * 8388608);

    split_all<<<2048, 256, 0, stream>>>(x, wup, wdown, xh, xl, wh, wd, colsum);

    up_mfma<<<dim3(32, 32), 256, 0, stream>>>(xh, xl, wh, beta, Tp, rate, colsum);

    finalize_rpu<<<FDIM / 256, 256, 0, stream>>>(colsum, out_rpu);

    down_mfma<<<dim3(DDIM / 128, N_ROWS / 128), 512, 0, stream>>>(rate, wd, out);
}

// Round 11
// 151.619 us; speedup vs baseline: 1.0628x; 1.0628x over previous
//
#include <hip/hip_runtime.h>

// Dims fixed by setup_inputs: B=2, S=2048, D=1024, F=4096, T=8
#define N_ROWS 4096
#define DDIM   1024
#define FDIM   4096

typedef unsigned short u16;
typedef __attribute__((ext_vector_type(8))) _Float16 f16x8;
typedef __attribute__((ext_vector_type(4))) float f32x4;

#define MFMA16(a, b, c) __builtin_amdgcn_mfma_f32_16x16x32_f16((a), (b), (c), 0, 0, 0)

static __device__ __forceinline__ u16 f2h_bits(float f) {
    _Float16 h = (_Float16)f;
    return __builtin_bit_cast(u16, h);
}
static __device__ __forceinline__ void gload_lds16(const u16* g, u16* l) {
    __builtin_amdgcn_global_load_lds((const __attribute__((address_space(1))) unsigned*)g,
                                     (__attribute__((address_space(3))) unsigned*)l, 16, 0, 0);
}

// ---- fused prepass: x -> (xh, xl) fp16 ; wup -> wh ; wdown -> wd ; zero colsum
__global__ __launch_bounds__(256) void split_all(
    const float* __restrict__ x, const float* __restrict__ wup,
    const float* __restrict__ wdown,
    u16* __restrict__ xh, u16* __restrict__ xl,
    u16* __restrict__ wh, u16* __restrict__ wd, float* __restrict__ colsum)
{
    const int N4 = (N_ROWS * DDIM) / 4;
    int i = blockIdx.x * 256 + threadIdx.x;
    if (i < FDIM / 4) ((float4*)colsum)[i] = (float4){0.f, 0.f, 0.f, 0.f};
    const int stride = gridDim.x * 256;
    for (; i < 3 * N4; i += stride) {
        const int r = i >> 20;            // N4 == 2^20
        const int j = i & (N4 - 1);
        if (r == 0) {
            float4 v = ((const float4*)x)[j];
            ushort4 h, l;
            h.x = f2h_bits(v.x); h.y = f2h_bits(v.y);
            h.z = f2h_bits(v.z); h.w = f2h_bits(v.w);
            l.x = f2h_bits(v.x - (float)__builtin_bit_cast(_Float16, h.x));
            l.y = f2h_bits(v.y - (float)__builtin_bit_cast(_Float16, h.y));
            l.z = f2h_bits(v.z - (float)__builtin_bit_cast(_Float16, h.z));
            l.w = f2h_bits(v.w - (float)__builtin_bit_cast(_Float16, h.w));
            ((ushort4*)xh)[j] = h;
            ((ushort4*)xl)[j] = l;
        } else {
            const float4 v = (r == 1) ? ((const float4*)wup)[j] : ((const float4*)wdown)[j];
            ushort4 h;
            h.x = f2h_bits(v.x); h.y = f2h_bits(v.y);
            h.z = f2h_bits(v.z); h.w = f2h_bits(v.w);
            if (r == 1) ((ushort4*)wh)[j] = h; else ((ushort4*)wd)[j] = h;
        }
    }
}

// ---- up-GEMM: 128x256 tile, BK=64, 8 waves (2Mx4N, wave-tile 64x64),
//      fp16 2-product (h = xh*wh + xl*wh), corrected 4-phase/tile schedule:
//      uniform vmcnt(8) at ph1 guarantees the WHOLE current tile landed
//      (outstanding = next tile's 8 loads); stages go in ph3 (A) / ph4 (B)
//      after their regions' reads completed block-wide. vmcnt(0) only on
//      the last tile. LDS: XH[2][128][64] 32K + XL 32K + WH[2][256][64] 64K
//      = 128 KiB. Fused LIF + column-sum epilogue. ----
__global__ __launch_bounds__(512, 1) void up_mfma(
    const u16* __restrict__ xh, const u16* __restrict__ xl,
    const u16* __restrict__ wh,
    const float* __restrict__ beta, const int* __restrict__ Tp,
    u16* __restrict__ rate, float* __restrict__ colsum)
{
    __shared__ __align__(16) u16 lds[65536];   // 128 KiB

    const int t = threadIdx.x;
    const int l = t & 63, w = t >> 6;
    const int wm = w >> 2, wn = w & 3;         // 2M x 4N, wave-tile 64x64

    // per-XCD 8bm x 8bn rectangle (grid 32bm x 16bn = 512 blocks)
    const int flat = blockIdx.y * gridDim.x + blockIdx.x;   // 0..511
    const int xcd = flat & 7, wi = flat >> 3;               // wi 0..63
    const int bm = ((xcd & 3) * 8 + (wi & 7)) * 128;
    const int bn = ((xcd >> 2) * 8 + (wi >> 3)) * 256;

    // staging: dest linear t*16B within each 8KB issue (64 rows x 64 k);
    // source k pre-swizzled (involution with read-side XOR, key = row&7)
    const int srow  = t >> 3;                               // 0..63
    const int skoff = (((t & 7) ^ ((t >> 3) & 7)) << 3);
    const int dst   = t * 8;

    // A region: xh [buf][128][64] at 0 / xl at 16384; B: wh [buf][256][64] at 32768
#define STG_A(buf, step) do {                                                 \
    const size_t kk = ((size_t)(step) << 6) + skoff;                          \
    const size_t g0 = (size_t)(bm + srow) * DDIM + kk;                        \
    const size_t g1 = (size_t)(bm + 64 + srow) * DDIM + kk;                   \
    gload_lds16(xh + g0, &lds[(buf) * 8192 + dst]);                           \
    gload_lds16(xh + g1, &lds[(buf) * 8192 + 4096 + dst]);                    \
    gload_lds16(xl + g0, &lds[16384 + (buf) * 8192 + dst]);                   \
    gload_lds16(xl + g1, &lds[16384 + (buf) * 8192 + 4096 + dst]);            \
} while (0)
#define STG_B(buf, step) do {                                                 \
    const size_t kk = ((size_t)(step) << 6) + skoff;                          \
    _Pragma("unroll") for (int q = 0; q < 4; ++q)                             \
        gload_lds16(wh + (size_t)(bn + q * 64 + srow) * DDIM + kk,            \
                    &lds[32768 + (buf) * 16384 + q * 4096 + dst]);            \
} while (0)

    const int lr = l & 15, lk = l >> 4;

#define RD_A(buf, mh, AH, AL) do {                                            \
    _Pragma("unroll") for (int mi = 0; mi < 2; ++mi) {                        \
        const int rowin = wm * 64 + ((mh) * 2 + mi) * 16 + lr;                \
        const int base = (buf) * 8192 + rowin * 64;                           \
        const int kx = rowin & 7;                                             \
        _Pragma("unroll") for (int kh = 0; kh < 2; ++kh) {                    \
            const int off = base + (((kh * 4 + lk) ^ kx) << 3);               \
            AH[mi][kh] = *(const f16x8*)&lds[off];                            \
            AL[mi][kh] = *(const f16x8*)&lds[16384 + off];                    \
        } } } while (0)

#define RD_B(buf, nh, BB) do {                                                \
    _Pragma("unroll") for (int ni = 0; ni < 2; ++ni) {                        \
        const int rowin = wn * 64 + ((nh) * 2 + ni) * 16 + lr;                \
        const int base = 32768 + (buf) * 16384 + rowin * 64;                  \
        const int kx = rowin & 7;                                             \
        _Pragma("unroll") for (int kh = 0; kh < 2; ++kh)                      \
            BB[ni][kh] = *(const f16x8*)&lds[base + (((kh * 4 + lk) ^ kx) << 3)]; \
    } } while (0)

#define QUAD(mh, nh, AH, AL, BB) do {                                         \
    __builtin_amdgcn_s_setprio(1);                                            \
    _Pragma("unroll") for (int mi = 0; mi < 2; ++mi)                          \
    _Pragma("unroll") for (int ni = 0; ni < 2; ++ni) {                        \
        f32x4 c = acc[(mh) * 2 + mi][(nh) * 2 + ni];                          \
        c = MFMA16(AH[mi][0], BB[ni][0], c);                                  \
        c = MFMA16(AL[mi][0], BB[ni][0], c);                                  \
        c = MFMA16(AH[mi][1], BB[ni][1], c);                                  \
        c = MFMA16(AL[mi][1], BB[ni][1], c);                                  \
        acc[(mh) * 2 + mi][(nh) * 2 + ni] = c;                                \
    }                                                                         \
    __builtin_amdgcn_s_setprio(0);                                            \
} while (0)

#define BAR_IN()  __builtin_amdgcn_s_barrier();                               \
    asm volatile("s_waitcnt lgkmcnt(0)" ::: "memory");                        \
    __builtin_amdgcn_sched_barrier(0)
#define BAR_OUT() __builtin_amdgcn_s_barrier()

    f32x4 acc[4][4];
#pragma unroll
    for (int m = 0; m < 4; ++m)
#pragma unroll
        for (int n = 0; n < 4; ++n) acc[m][n] = (f32x4){0.f, 0.f, 0.f, 0.f};

    // prologue: stage tile 0 (buf0: A then B), tile 1 (buf1)
    STG_A(0, 0); STG_B(0, 0);
    STG_A(1, 1); STG_B(1, 1);
    asm volatile("s_waitcnt vmcnt(8)" ::: "memory");   // tile 0 fully landed
    __builtin_amdgcn_s_barrier();

    const int NT = DDIM / 64;        // 16 K-tiles
#pragma unroll 2
    for (int ts = 0; ts < NT; ++ts) {
        const int buf = ts & 1;
        const bool more = (ts + 2 < NT);
        f16x8 ah0[2][2], al0[2][2], ah1[2][2], al1[2][2], b0[2][2], b1[2][2];

        // ph1: read A(q0,q1)+B(q0,q1); whole tile ts guaranteed landed
        RD_A(buf, 0, ah0, al0); RD_B(buf, 0, b0);
        if (ts + 1 < NT) { asm volatile("s_waitcnt vmcnt(8)" ::: "memory"); }
        else             { asm volatile("s_waitcnt vmcnt(0)" ::: "memory"); }
        BAR_IN(); QUAD(0, 0, ah0, al0, b0); BAR_OUT();

        // ph2: read A(q2,q3)
        RD_A(buf, 1, ah1, al1);
        BAR_IN(); QUAD(1, 0, ah1, al1, b0); BAR_OUT();

        // ph3: read B(q2,q3); stage A(ts+2) (A-reads of buf done block-wide)
        RD_B(buf, 1, b1);
        if (more) STG_A(buf, ts + 2);
        BAR_IN(); QUAD(1, 1, ah1, al1, b1); BAR_OUT();

        // ph4: stage B(ts+2) (B-reads of buf done block-wide); held regs
        if (more) STG_B(buf, ts + 2);
        BAR_IN(); QUAD(0, 1, ah0, al0, b1); BAR_OUT();
    }
#undef STG_A
#undef STG_B
#undef RD_A
#undef RD_B
#undef QUAD
#undef BAR_IN
#undef BAR_OUT

    // ---- epilogue: LIF recurrence, rate write, fused column sums ----
    const int T = Tp[0];
    const float invT = 1.0f / (float)T;
    const int fbase = bn + wn * 64;
    float betav[4], colacc[4];
#pragma unroll
    for (int n = 0; n < 4; ++n) { betav[n] = beta[fbase + n * 16 + lr]; colacc[n] = 0.f; }

#pragma unroll
    for (int m = 0; m < 4; ++m) {
#pragma unroll
        for (int r = 0; r < 4; ++r) {
            const int row = bm + wm * 64 + m * 16 + lk * 4 + r;
            u16* rp = rate + (size_t)row * FDIM + fbase + lr;
#pragma unroll
            for (int n = 0; n < 4; ++n) {
                const float h = acc[m][n][r];
                const float bet = betav[n];
                float v = 0.f, ss = 0.f;
                if (T == 8) {
#pragma unroll
                    for (int tt = 0; tt < 8; ++tt) {
                        v = fmaf(bet, v, h);
                        float s = (v > 1.0f) ? 1.0f : 0.0f;
                        ss += s; v -= s;
                    }
                } else {
                    for (int tt = 0; tt < T; ++tt) {
                        v = fmaf(bet, v, h);
                        float s = (v > 1.0f) ? 1.0f : 0.0f;
                        ss += s; v -= s;
                    }
                }
                const float rv = ss * invT;                 // exact k/8 (fp16-exact)
                rp[n * 16] = f2h_bits(rv);
                colacc[n] += rv;
            }
        }
    }
#pragma unroll
    for (int n = 0; n < 4; ++n) {
        float ca = colacc[n];
        ca += __shfl_xor(ca, 16, 64);
        ca += __shfl_xor(ca, 32, 64);
        if (lk == 0) atomicAdd(&colsum[fbase + n * 16 + lr], ca);  // exact eighths
    }
}

// ---- down-GEMM: 128x128 tile, BK=64, 8 waves (2Mx4N, wave-tile 64x32),
//      fp16 16x16x32 MFMA, 3-slot counted-vmcnt rotation, 0-conflict XOR LDS.
//      out = rate(fp16) @ wd(fp16)^T, fp32 out ----
__global__ __launch_bounds__(512, 1) void down_mfma(
    const u16* __restrict__ rate, const u16* __restrict__ wd,
    float* __restrict__ out)
{
    __shared__ __align__(16) u16 lds[3 * 16384];

    const int t = threadIdx.x;
    const int l = t & 63, w = t >> 6;
    const int wm = w >> 2, wn = w & 3;          // wave tile 64x32

    const int flat = blockIdx.y * gridDim.x + blockIdx.x;   // 0..255
    const int xcd = flat & 7, wi = flat >> 3;               // wi 0..31
    const int bm = ((xcd & 3) * 8 + (wi & 7)) * 128;
    const int bn = ((xcd >> 2) * 4 + (wi >> 3)) * 128;

    const int srow = t >> 3;                                // 0..63
    const int koff = (((t & 7) ^ ((t >> 3) & 7)) << 3);
    const size_t gA0 = (size_t)(bm + srow) * FDIM + koff;
    const size_t gA1 = gA0 + (size_t)64 * FDIM;
    const size_t gB0 = (size_t)(bn + srow) * FDIM + koff;
    const size_t gB1 = gB0 + (size_t)64 * FDIM;
    const int dst = t * 8;

#define STD(slot, step) do {                                                  \
    const size_t k0_ = (size_t)(step) << 6;                                   \
    u16* Lb_ = &lds[(slot) * 16384];                                          \
    gload_lds16(rate + gA0 + k0_, Lb_ + dst);                                 \
    gload_lds16(rate + gA1 + k0_, Lb_ + 4096 + dst);                          \
    gload_lds16(wd + gB0 + k0_, Lb_ + 8192 + dst);                            \
    gload_lds16(wd + gB1 + k0_, Lb_ + 12288 + dst);                           \
} while (0)

    const int lr = l & 15, lk = l >> 4;
    const int key = lr & 7;
    const int ps0 = ((0 * 4 + lk) ^ key) << 3;
    const int ps1 = ((1 * 4 + lk) ^ key) << 3;

    f32x4 acc[4][2];
#pragma unroll
    for (int m = 0; m < 4; ++m) {
        acc[m][0] = (f32x4){0.f, 0.f, 0.f, 0.f};
        acc[m][1] = (f32x4){0.f, 0.f, 0.f, 0.f};
    }

    STD(0, 0);
    STD(1, 1);

    const int NT = FDIM / 64;   // 64
#pragma unroll 1
    for (int ts = 0; ts < NT; ++ts) {
        if (ts + 1 < NT) { asm volatile("s_waitcnt vmcnt(4)" ::: "memory"); }
        else             { asm volatile("s_waitcnt vmcnt(0)" ::: "memory"); }
        __builtin_amdgcn_s_barrier();

        if (ts + 2 < NT) STD((ts + 2) % 3, ts + 2);

        const int sb = (ts % 3) * 16384;
        f16x8 a[4][2], b[2][2];
#pragma unroll
        for (int m = 0; m < 4; ++m) {
            const int ro = sb + (wm * 64 + m * 16 + lr) * 64;
            a[m][0] = *(const f16x8*)&lds[ro + ps0];
            a[m][1] = *(const f16x8*)&lds[ro + ps1];
        }
#pragma unroll
        for (int n = 0; n < 2; ++n) {
            const int ro = sb + 8192 + (wn * 32 + n * 16 + lr) * 64;
            b[n][0] = *(const f16x8*)&lds[ro + ps0];
            b[n][1] = *(const f16x8*)&lds[ro + ps1];
        }
        __builtin_amdgcn_s_setprio(1);
#pragma unroll
        for (int m = 0; m < 4; ++m)
#pragma unroll
            for (int n = 0; n < 2; ++n) {
                f32x4 c = acc[m][n];
                c = MFMA16(a[m][0], b[n][0], c);
                c = MFMA16(a[m][1], b[n][1], c);
                acc[m][n] = c;
            }
        __builtin_amdgcn_s_setprio(0);
    }
#undef STD

#pragma unroll
    for (int n = 0; n < 2; ++n) {
        const int d = bn + wn * 32 + n * 16 + lr;
#pragma unroll
        for (int m = 0; m < 4; ++m) {
            const int row0 = bm + wm * 64 + m * 16 + lk * 4;
#pragma unroll
            for (int r = 0; r < 4; ++r)
                out[(size_t)(row0 + r) * DDIM + d] = acc[m][n][r];
        }
    }
}

// ---- rate_per_unit ----
__global__ void finalize_rpu(const float* __restrict__ colsum, float* __restrict__ out_rpu) {
    const int f = blockIdx.x * 256 + threadIdx.x;
    out_rpu[f] = colsum[f] * (1.0f / (float)N_ROWS);
}

extern "C" void kernel_launch(void* const* d_in, const int* in_sizes, int n_in,
                              void* d_out, int out_size, void* d_ws, size_t ws_size,
                              hipStream_t stream) {
    const float* x     = (const float*)d_in[0];
    const float* wup   = (const float*)d_in[1];
    const float* wdown = (const float*)d_in[2];
    const float* beta  = (const float*)d_in[3];
    const int*   Tp    = (const int*)d_in[4];

    float* out     = (float*)d_out;
    float* out_rpu = out + (size_t)N_ROWS * DDIM;

    char* ws = (char*)d_ws;
    u16* rate = (u16*)ws;                                   // 33,554,432 B
    u16* xh   = (u16*)(ws + 33554432);
    u16* xl   = (u16*)(ws + 33554432 + 8388608);
    u16* wh   = (u16*)(ws + 33554432 + 2 * 8388608);
    u16* wd   = (u16*)(ws + 33554432 + 3 * 8388608);
    float* colsum = (float*)(ws + 33554432 + 4 * 8388608);

    split_all<<<2048, 256, 0, stream>>>(x, wup, wdown, xh, xl, wh, wd, colsum);

    up_mfma<<<dim3(16, 32), 512, 0, stream>>>(xh, xl, wh, beta, Tp, rate, colsum);

    finalize_rpu<<<FDIM / 256, 256, 0, stream>>>(colsum, out_rpu);

    down_mfma<<<dim3(DDIM / 128, N_ROWS / 128), 512, 0, stream>>>(rate, wd, out);
}

// Round 12
// 124.273 us; speedup vs baseline: 1.2967x; 1.2200x over previous
//
#include <hip/hip_runtime.h>

// Dims fixed by setup_inputs: B=2, S=2048, D=1024, F=4096, T=8
#define N_ROWS 4096
#define DDIM   1024
#define FDIM   4096

typedef unsigned short u16;
typedef __attribute__((ext_vector_type(8))) _Float16 f16x8;
typedef __attribute__((ext_vector_type(4))) float f32x4;

#define MFMA16(a, b, c) __builtin_amdgcn_mfma_f32_16x16x32_f16((a), (b), (c), 0, 0, 0)

static __device__ __forceinline__ u16 f2h_bits(float f) {
    _Float16 h = (_Float16)f;
    return __builtin_bit_cast(u16, h);
}
static __device__ __forceinline__ void gload_lds16(const u16* g, u16* l) {
    __builtin_amdgcn_global_load_lds((const __attribute__((address_space(1))) unsigned*)g,
                                     (__attribute__((address_space(3))) unsigned*)l, 16, 0, 0);
}

// ---- fused prepass: x -> xh fp16 ; wup -> wh ; wdown -> wd ; zero colsum ----
__global__ __launch_bounds__(256) void split_all(
    const float* __restrict__ x, const float* __restrict__ wup,
    const float* __restrict__ wdown,
    u16* __restrict__ xh, u16* __restrict__ wh, u16* __restrict__ wd,
    float* __restrict__ colsum)
{
    const int N4 = (N_ROWS * DDIM) / 4;   // 2^20 float4 per array
    int i = blockIdx.x * 256 + threadIdx.x;
    if (i < FDIM / 4) ((float4*)colsum)[i] = (float4){0.f, 0.f, 0.f, 0.f};
    const int stride = gridDim.x * 256;
    for (; i < 3 * N4; i += stride) {
        const int r = i >> 20;
        const int j = i & (N4 - 1);
        const float4 v = (r == 0) ? ((const float4*)x)[j]
                       : (r == 1) ? ((const float4*)wup)[j]
                                  : ((const float4*)wdown)[j];
        ushort4 h;
        h.x = f2h_bits(v.x); h.y = f2h_bits(v.y);
        h.z = f2h_bits(v.z); h.w = f2h_bits(v.w);
        if (r == 0)      ((ushort4*)xh)[j] = h;
        else if (r == 1) ((ushort4*)wh)[j] = h;
        else             ((ushort4*)wd)[j] = h;
    }
}

// ---- up-GEMM: 256x256 tile, BK=32, 8 waves (4Mx2N, wave-tile 64x128),
//      fp16 single product (h = xh*wh), 3-slot counted-vmcnt rotation
//      (down-proven schedule shape: 4 gloads/tile, vmcnt(4), never 0
//      mid-loop), 0-conflict XOR LDS, fused LIF + column-sum epilogue. ----
__global__ __launch_bounds__(512, 1) void up_mfma(
    const u16* __restrict__ xh, const u16* __restrict__ wh,
    const float* __restrict__ beta, const int* __restrict__ Tp,
    u16* __restrict__ rate, float* __restrict__ colsum)
{
    // slot = A[256][32] (16KB) + B[256][32] (16KB) = 32KB; 3 slots = 96KB
    __shared__ __align__(16) u16 lds[3 * 16384];

    const int t = threadIdx.x;
    const int l = t & 63, w = t >> 6;
    const int wm = w >> 1, wn = w & 1;          // wave-tile 64(M) x 128(N)

    // per-XCD 4bm x 8bn rectangle (grid 16x16 = 256 blocks)
    const int flat = blockIdx.y * gridDim.x + blockIdx.x;   // 0..255
    const int xcd = flat & 7, wi = flat >> 3;               // wi 0..31
    const int bm = ((xcd & 3) * 4 + (wi & 3)) * 256;
    const int bn = ((xcd >> 2) * 8 + (wi >> 2)) * 256;

    // staging: dest linear t*16B (each issue = 8KB = 128 rows x 64B);
    // source k pre-swizzled (involution with read-side XOR, key=(row>>1)&3)
    const int koff = (((t & 3) ^ ((t >> 3) & 3)) << 3);
    const size_t gA0 = (size_t)(bm + (t >> 2)) * DDIM + koff;
    const size_t gA1 = gA0 + (size_t)128 * DDIM;
    const size_t gB0 = (size_t)(bn + (t >> 2)) * DDIM + koff;
    const size_t gB1 = gB0 + (size_t)128 * DDIM;
    const int dst = t * 8;

#define STG(slot, step) do {                                                  \
    const size_t k0_ = (size_t)(step) << 5;                                   \
    u16* Lb_ = &lds[(slot) * 16384];                                          \
    gload_lds16(xh + gA0 + k0_, Lb_ + dst);                                   \
    gload_lds16(xh + gA1 + k0_, Lb_ + 4096 + dst);                            \
    gload_lds16(wh + gB0 + k0_, Lb_ + 8192 + dst);                            \
    gload_lds16(wh + gB1 + k0_, Lb_ + 12288 + dst);                           \
} while (0)

    // fragment reads (0-conflict XOR, proven R4/R6/R8)
    const int lr = l & 15, lk = l >> 4;
    const int psl = ((lk ^ ((lr >> 1) & 3)) << 3);

    f32x4 acc[4][8];
#pragma unroll
    for (int m = 0; m < 4; ++m)
#pragma unroll
        for (int n = 0; n < 8; ++n) acc[m][n] = (f32x4){0.f, 0.f, 0.f, 0.f};

    // prologue: stage tiles 0,1 (8 loads in flight)
    STG(0, 0);
    STG(1, 1);

    const int NT = DDIM / 32;   // 32
#pragma unroll 1
    for (int ts = 0; ts < NT; ++ts) {
        // counted wait: tile ts's 4 loads landed (<=4 newest may pend)
        if (ts + 1 < NT) { asm volatile("s_waitcnt vmcnt(4)" ::: "memory"); }
        else             { asm volatile("s_waitcnt vmcnt(0)" ::: "memory"); }
        __builtin_amdgcn_s_barrier();

        // stage tile ts+2 into the slot last read at ts-1 (race-free)
        if (ts + 2 < NT) STG((ts + 2) % 3, ts + 2);

        const int sb = (ts % 3) * 16384;
        f16x8 a[4], b[8];
#pragma unroll
        for (int m = 0; m < 4; ++m) {
            const int rowin = wm * 64 + m * 16 + lr;   // 0..255
            a[m] = *(const f16x8*)&lds[sb + (rowin >> 7) * 4096 + (rowin & 127) * 32 + psl];
        }
#pragma unroll
        for (int n = 0; n < 8; ++n) {
            const int rowin = wn * 128 + n * 16 + lr;  // 0..255
            b[n] = *(const f16x8*)&lds[sb + 8192 + (rowin >> 7) * 4096 + (rowin & 127) * 32 + psl];
        }
        __builtin_amdgcn_s_setprio(1);
#pragma unroll
        for (int m = 0; m < 4; ++m)
#pragma unroll
            for (int n = 0; n < 8; ++n)
                acc[m][n] = MFMA16(a[m], b[n], acc[m][n]);
        __builtin_amdgcn_s_setprio(0);
    }
#undef STG

    // ---- epilogue: LIF recurrence, rate write, fused column sums ----
    const int T = Tp[0];
    const float invT = 1.0f / (float)T;
    const int fbase = bn + wn * 128;
    float betav[8], colacc[8];
#pragma unroll
    for (int n = 0; n < 8; ++n) { betav[n] = beta[fbase + n * 16 + lr]; colacc[n] = 0.f; }

#pragma unroll
    for (int m = 0; m < 4; ++m) {
#pragma unroll
        for (int r = 0; r < 4; ++r) {
            const int row = bm + wm * 64 + m * 16 + lk * 4 + r;
            u16* rp = rate + (size_t)row * FDIM + fbase + lr;
#pragma unroll
            for (int n = 0; n < 8; ++n) {
                const float h = acc[m][n][r];
                const float bet = betav[n];
                float v = 0.f, ss = 0.f;
                if (T == 8) {
#pragma unroll
                    for (int tt = 0; tt < 8; ++tt) {
                        v = fmaf(bet, v, h);
                        float s = (v > 1.0f) ? 1.0f : 0.0f;
                        ss += s; v -= s;
                    }
                } else {
                    for (int tt = 0; tt < T; ++tt) {
                        v = fmaf(bet, v, h);
                        float s = (v > 1.0f) ? 1.0f : 0.0f;
                        ss += s; v -= s;
                    }
                }
                const float rv = ss * invT;                 // exact k/8 (fp16-exact)
                rp[n * 16] = f2h_bits(rv);
                colacc[n] += rv;
            }
        }
    }
#pragma unroll
    for (int n = 0; n < 8; ++n) {
        float ca = colacc[n];
        ca += __shfl_xor(ca, 16, 64);
        ca += __shfl_xor(ca, 32, 64);
        if (lk == 0) atomicAdd(&colsum[fbase + n * 16 + lr], ca);  // exact eighths
    }
}

// ---- down-GEMM: 128x128 tile, BK=64, 8 waves (2Mx4N, wave-tile 64x32),
//      fp16 16x16x32 MFMA, 3-slot counted-vmcnt rotation, 0-conflict XOR LDS.
//      out = rate(fp16) @ wd(fp16)^T, fp32 out. (R8-proven, unchanged) ----
__global__ __launch_bounds__(512, 1) void down_mfma(
    const u16* __restrict__ rate, const u16* __restrict__ wd,
    float* __restrict__ out)
{
    __shared__ __align__(16) u16 lds[3 * 16384];

    const int t = threadIdx.x;
    const int l = t & 63, w = t >> 6;
    const int wm = w >> 2, wn = w & 3;          // wave tile 64x32

    const int flat = blockIdx.y * gridDim.x + blockIdx.x;   // 0..255
    const int xcd = flat & 7, wi = flat >> 3;               // wi 0..31
    const int bm = ((xcd & 3) * 8 + (wi & 7)) * 128;
    const int bn = ((xcd >> 2) * 4 + (wi >> 3)) * 128;

    const int srow = t >> 3;                                // 0..63
    const int koff = (((t & 7) ^ ((t >> 3) & 7)) << 3);
    const size_t gA0 = (size_t)(bm + srow) * FDIM + koff;
    const size_t gA1 = gA0 + (size_t)64 * FDIM;
    const size_t gB0 = (size_t)(bn + srow) * FDIM + koff;
    const size_t gB1 = gB0 + (size_t)64 * FDIM;
    const int dst = t * 8;

#define STD(slot, step) do {                                                  \
    const size_t k0_ = (size_t)(step) << 6;                                   \
    u16* Lb_ = &lds[(slot) * 16384];                                          \
    gload_lds16(rate + gA0 + k0_, Lb_ + dst);                                 \
    gload_lds16(rate + gA1 + k0_, Lb_ + 4096 + dst);                          \
    gload_lds16(wd + gB0 + k0_, Lb_ + 8192 + dst);                            \
    gload_lds16(wd + gB1 + k0_, Lb_ + 12288 + dst);                           \
} while (0)

    const int lr = l & 15, lk = l >> 4;
    const int key = lr & 7;
    const int ps0 = ((0 * 4 + lk) ^ key) << 3;
    const int ps1 = ((1 * 4 + lk) ^ key) << 3;

    f32x4 acc[4][2];
#pragma unroll
    for (int m = 0; m < 4; ++m) {
        acc[m][0] = (f32x4){0.f, 0.f, 0.f, 0.f};
        acc[m][1] = (f32x4){0.f, 0.f, 0.f, 0.f};
    }

    STD(0, 0);
    STD(1, 1);

    const int NT = FDIM / 64;   // 64
#pragma unroll 1
    for (int ts = 0; ts < NT; ++ts) {
        if (ts + 1 < NT) { asm volatile("s_waitcnt vmcnt(4)" ::: "memory"); }
        else             { asm volatile("s_waitcnt vmcnt(0)" ::: "memory"); }
        __builtin_amdgcn_s_barrier();

        if (ts + 2 < NT) STD((ts + 2) % 3, ts + 2);

        const int sb = (ts % 3) * 16384;
        f16x8 a[4][2], b[2][2];
#pragma unroll
        for (int m = 0; m < 4; ++m) {
            const int ro = sb + (wm * 64 + m * 16 + lr) * 64;
            a[m][0] = *(const f16x8*)&lds[ro + ps0];
            a[m][1] = *(const f16x8*)&lds[ro + ps1];
        }
#pragma unroll
        for (int n = 0; n < 2; ++n) {
            const int ro = sb + 8192 + (wn * 32 + n * 16 + lr) * 64;
            b[n][0] = *(const f16x8*)&lds[ro + ps0];
            b[n][1] = *(const f16x8*)&lds[ro + ps1];
        }
        __builtin_amdgcn_s_setprio(1);
#pragma unroll
        for (int m = 0; m < 4; ++m)
#pragma unroll
            for (int n = 0; n < 2; ++n) {
                f32x4 c = acc[m][n];
                c = MFMA16(a[m][0], b[n][0], c);
                c = MFMA16(a[m][1], b[n][1], c);
                acc[m][n] = c;
            }
        __builtin_amdgcn_s_setprio(0);
    }
#undef STD

#pragma unroll
    for (int n = 0; n < 2; ++n) {
        const int d = bn + wn * 32 + n * 16 + lr;
#pragma unroll
        for (int m = 0; m < 4; ++m) {
            const int row0 = bm + wm * 64 + m * 16 + lk * 4;
#pragma unroll
            for (int r = 0; r < 4; ++r)
                out[(size_t)(row0 + r) * DDIM + d] = acc[m][n][r];
        }
    }
}

// ---- rate_per_unit ----
__global__ void finalize_rpu(const float* __restrict__ colsum, float* __restrict__ out_rpu) {
    const int f = blockIdx.x * 256 + threadIdx.x;
    out_rpu[f] = colsum[f] * (1.0f / (float)N_ROWS);
}

extern "C" void kernel_launch(void* const* d_in, const int* in_sizes, int n_in,
                              void* d_out, int out_size, void* d_ws, size_t ws_size,
                              hipStream_t stream) {
    const float* x     = (const float*)d_in[0];
    const float* wup   = (const float*)d_in[1];
    const float* wdown = (const float*)d_in[2];
    const float* beta  = (const float*)d_in[3];
    const int*   Tp    = (const int*)d_in[4];

    float* out     = (float*)d_out;
    float* out_rpu = out + (size_t)N_ROWS * DDIM;

    char* ws = (char*)d_ws;
    u16* rate = (u16*)ws;                                   // 33,554,432 B
    u16* xh   = (u16*)(ws + 33554432);
    u16* wh   = (u16*)(ws + 33554432 + 8388608);
    u16* wd   = (u16*)(ws + 33554432 + 2 * 8388608);
    float* colsum = (float*)(ws + 33554432 + 3 * 8388608);

    split_all<<<2048, 256, 0, stream>>>(x, wup, wdown, xh, wh, wd, colsum);

    up_mfma<<<dim3(16, 16), 512, 0, stream>>>(xh, wh, beta, Tp, rate, colsum);

    finalize_rpu<<<FDIM / 256, 256, 0, stream>>>(colsum, out_rpu);

    down_mfma<<<dim3(DDIM / 128, N_ROWS / 128), 512, 0, stream>>>(rate, wd, out);
}